// Round 1
// baseline (3336.885 us; speedup 1.0000x reference)
//
#include <hip/hip_runtime.h>
#include <math.h>

#define BB 32
#define CC 256
#define HWt 1024          // H*W
#define NN 32768          // B*H*W
#define KK 2048
#define RQDEPTH 4

// ===== numpy pairwise sum-of-squares, blocksize-128 tree, bit-exact =====
__device__ __forceinline__ float pw128sq(const float4* __restrict__ a4) {
  float r[8];
  {
    float4 p = a4[0], q = a4[1];
    r[0] = __fmul_rn(p.x, p.x); r[1] = __fmul_rn(p.y, p.y);
    r[2] = __fmul_rn(p.z, p.z); r[3] = __fmul_rn(p.w, p.w);
    r[4] = __fmul_rn(q.x, q.x); r[5] = __fmul_rn(q.y, q.y);
    r[6] = __fmul_rn(q.z, q.z); r[7] = __fmul_rn(q.w, q.w);
  }
  for (int i = 1; i < 16; ++i) {
    float4 p = a4[2 * i], q = a4[2 * i + 1];
    r[0] = __fadd_rn(r[0], __fmul_rn(p.x, p.x));
    r[1] = __fadd_rn(r[1], __fmul_rn(p.y, p.y));
    r[2] = __fadd_rn(r[2], __fmul_rn(p.z, p.z));
    r[3] = __fadd_rn(r[3], __fmul_rn(p.w, p.w));
    r[4] = __fadd_rn(r[4], __fmul_rn(q.x, q.x));
    r[5] = __fadd_rn(r[5], __fmul_rn(q.y, q.y));
    r[6] = __fadd_rn(r[6], __fmul_rn(q.z, q.z));
    r[7] = __fadd_rn(r[7], __fmul_rn(q.w, q.w));
  }
  return __fadd_rn(__fadd_rn(__fadd_rn(r[0], r[1]), __fadd_rn(r[2], r[3])),
                   __fadd_rn(__fadd_rn(r[4], r[5]), __fadd_rn(r[6], r[7])));
}

// ---------------- prep: z [B,C,H,W] -> resid [N,C] ----------------
__global__ void k_ztrans(const float* __restrict__ z, float* __restrict__ resid) {
  __shared__ float tile[32][33];
  int b = blockIdx.z, c0 = blockIdx.y * 32, hw0 = blockIdx.x * 32;
  int tx = threadIdx.x & 31, ty = threadIdx.x >> 5;
  for (int i = ty; i < 32; i += 8)
    tile[i][tx] = z[((size_t)b * CC + c0 + i) * HWt + hw0 + tx];
  __syncthreads();
  for (int i = ty; i < 32; i += 8)
    resid[((size_t)b * HWt + hw0 + i) * CC + c0 + tx] = tile[tx][i];
}

// ---------------- prep: cb [K,C] -> cbT [C,K] ----------------
__global__ void k_cbtrans(const float* __restrict__ cb, float* __restrict__ cbT) {
  __shared__ float tile[32][33];
  int k0 = blockIdx.x * 32, c0 = blockIdx.y * 32;
  int tx = threadIdx.x & 31, ty = threadIdx.x >> 5;
  for (int i = ty; i < 32; i += 8)
    tile[i][tx] = cb[(size_t)(k0 + i) * CC + c0 + tx];
  __syncthreads();
  for (int i = ty; i < 32; i += 8)
    cbT[(size_t)(c0 + i) * KK + k0 + tx] = tile[tx][i];
}

// ---------------- B_k = np.sum(cb**2, axis=1) bit-exact ----------------
__global__ void k_bnorm(const float* __restrict__ cb, float* __restrict__ Bcol) {
  int k = blockIdx.x * 256 + threadIdx.x;
  if (k >= KK) return;
  const float4* row = (const float4*)(cb + (size_t)k * CC);
  Bcol[k] = __fadd_rn(pw128sq(row), pw128sq(row + 32));
}

__global__ void k_zero(int* counts) {
  int t = blockIdx.x * 256 + threadIdx.x;
  if (t < KK) counts[t] = 0;
}

// ---------------- bulk: np fp32 dists + first-argmin, software-pipelined ------
// Same math/argmin as the verified kernel (strict c-ascending fmaf per (n,k),
// fl(A+B)-2*acc, u64 (dist,k) lex first-argmin). New schedule:
//  * z tile (16 rows x 256) staged to LDS once per block; Arow recomputed
//    in-block from LDS with the identical pw128sq tree (k_anorm fused away).
//  * E (cbT fragments) double-buffered: loads for c4+1 issue before the FMA
//    block of c4 -> >=512 cycles of vmcnt cover.
//  * z served from LDS via a ring-8 / ahead-4 ds_read_b128 pipeline: step r
//    reads zr[r&7], writes zr[(r+4)&7] (distinct slots, static indices) ->
//    ds_read latency covered by 4 row-steps of FMAs, no scalar-cache thrash.
#define LOADE(E, C4V)                                                          \
  {                                                                            \
    _Pragma("unroll")                                                          \
    for (int cs = 0; cs < 4; ++cs)                                             \
      *(float4*)((E) + 4 * cs) =                                               \
          ((const float4*)(cbT + (size_t)(4 * (C4V) + cs) * KK + kbase))[lane];\
  }

#define FMA_BLOCK(E, C4V)                                                      \
  {                                                                            \
    _Pragma("unroll")                                                          \
    for (int r = 0; r < 16; ++r) {                                             \
      const float4 z4 = zr[r & 7];                                             \
      _Pragma("unroll")                                                        \
      for (int j = 0; j < 4; ++j) {                                            \
        float a = acc[r][j];                                                   \
        a = fmaf(z4.x, (E)[0 * 4 + j], a);  /* strict c-ascending chain */     \
        a = fmaf(z4.y, (E)[1 * 4 + j], a);                                     \
        a = fmaf(z4.z, (E)[2 * 4 + j], a);                                     \
        a = fmaf(z4.w, (E)[3 * 4 + j], a);                                     \
        acc[r][j] = a;                                                         \
      }                                                                        \
      { /* prefetch z for step r+4 (row (r+4)&15, col-block C4V or C4V+1) */   \
        const int pr = (r + 4) & 15;                                           \
        const int pc = (C4V) + ((r + 4) >> 4);                                 \
        zr[(r + 4) & 7] = *(const float4*)(zl + pr * 256 + 4 * pc);            \
      }                                                                        \
    }                                                                          \
  }

__global__ __launch_bounds__(256, 3) void k_bulk(const float* __restrict__ resid,
                                                 const float* __restrict__ cbT,
                                                 const float* __restrict__ Bcol,
                                                 int* __restrict__ idxAll,
                                                 float* __restrict__ idxOut,
                                                 int* __restrict__ counts, int depth) {
  __shared__ float zl[16 * 256];                 // 16 KiB z tile
  __shared__ float rowA[16];
  __shared__ unsigned long long sm[4][2][16];
  const int wave = __builtin_amdgcn_readfirstlane((int)(threadIdx.x >> 6));
  const int lane = threadIdx.x & 63;
  const int row0 = blockIdx.x * 16;

  // stage z tile -> LDS (coalesced float4)
  {
    const float4* src = (const float4*)(resid + (size_t)row0 * CC);
    for (int i = threadIdx.x; i < 16 * 64; i += 256)
      ((float4*)zl)[i] = src[i];
  }
  __syncthreads();
  // Arow for these 16 rows, bit-exact pw128 tree (k_anorm fused here)
  if (threadIdx.x < 16) {
    const float4* row = (const float4*)(zl + threadIdx.x * 256);
    rowA[threadIdx.x] = __fadd_rn(pw128sq(row), pw128sq(row + 32));
  }
  __syncthreads();

#pragma unroll 1
  for (int pass = 0; pass < 2; ++pass) {
    const int kbase = wave * 512 + pass * 256;
    float bk[4];
    *(float4*)bk = ((const float4*)(Bcol + kbase))[lane];   // long cover to epilogue

    float acc[16][4];
#pragma unroll
    for (int r = 0; r < 16; ++r)
#pragma unroll
      for (int j = 0; j < 4; ++j) acc[r][j] = 0.f;

    float E0[16], E1[16];
    float4 zr[8];
#pragma unroll
    for (int s = 0; s < 4; ++s) zr[s] = *(const float4*)(zl + s * 256); // rows 0..3 @ c4=0
    LOADE(E0, 0);

#pragma unroll 1
    for (int c4 = 0; c4 < 62; c4 += 2) {
      LOADE(E1, c4 + 1);
      FMA_BLOCK(E0, c4);
      LOADE(E0, c4 + 2);
      FMA_BLOCK(E1, c4 + 1);
    }
    // tail: c4 = 62, 63 (z prefetch over-reads stay inside zl; values unused)
    LOADE(E1, 63);
    FMA_BLOCK(E0, 62);
    FMA_BLOCK(E1, 63);

    // epilogue: dists + exact lex first-argmin for this pass
#pragma unroll
    for (int r = 0; r < 16; ++r) {
      const float Ar = rowA[r];
      unsigned long long b = ~0ull;
#pragma unroll
      for (int j = 0; j < 4; ++j) {
        float Cv = __fadd_rn(Ar, bk[j]);                         // fl32(A + B)
        float s  = __fsub_rn(Cv, __fadd_rn(acc[r][j], acc[r][j])); // fl32(C - 2M)
        unsigned long long pk =
            ((unsigned long long)__float_as_uint(s) << 32) |
            (unsigned int)(kbase + lane * 4 + j);
        if (pk < b) b = pk;
      }
      for (int m = 1; m < 64; m <<= 1) {
        unsigned long long o = __shfl_xor(b, m);
        if (o < b) b = o;
      }
      if (lane == 0) sm[wave][pass][r] = b;
    }
  }
  __syncthreads();
  // merge 4 waves x 2 passes per row
  if (threadIdx.x < 16) {
    unsigned long long b = ~0ull;
#pragma unroll
    for (int w = 0; w < 4; ++w)
#pragma unroll
      for (int p = 0; p < 2; ++p)
        if (sm[w][p][threadIdx.x] < b) b = sm[w][p][threadIdx.x];
    int wi = (int)(unsigned int)(b & 0xffffffffu);
    int n = row0 + (int)threadIdx.x;
    idxAll[depth * NN + n] = wi;
    idxOut[n] = (float)wi;
    atomicAdd(counts + wi, 1);
  }
}

// ------- update: resid -= q (fp32, np order), cum[d] = cum[d-1] + q, zst at d=3 -------
__global__ void k_update(const float* __restrict__ cb, const int* __restrict__ idxAll,
                         float* __restrict__ resid, float* __restrict__ cum,
                         float* __restrict__ zst, int depth) {
  __shared__ float qt[32][33];
  __shared__ float rt[32][33];
  int b = blockIdx.z, c0 = blockIdx.y * 32, hw0 = blockIdx.x * 32;
  int tx = threadIdx.x & 31, ty = threadIdx.x >> 5;
  const int* idx = idxAll + depth * NN;
  for (int i = ty; i < 32; i += 8) {
    int n = b * HWt + hw0 + i;
    int kk = idx[n];
    size_t fo = (size_t)n * CC + c0 + tx;
    float q = cb[(size_t)kk * CC + c0 + tx];
    float r = __fsub_rn(resid[fo], q);
    resid[fo] = r;
    qt[i][tx] = q;
    rt[i][tx] = r;
  }
  __syncthreads();
  const size_t PLANE = (size_t)NN * CC;
  for (int i = ty; i < 32; i += 8) {
    size_t oo = ((size_t)b * CC + c0 + i) * HWt + hw0 + tx;
    float q = qt[tx][i];
    float prevv = (depth == 0) ? 0.f : cum[(size_t)(depth - 1) * PLANE + oo];
    cum[(size_t)depth * PLANE + oo] = __fadd_rn(prevv, q);
    if (depth == 3) zst[oo] = rt[tx][i];
  }
}

// ---------------- perplexity ----------------
__global__ void k_perp(const int* __restrict__ counts, float* __restrict__ out) {
  __shared__ double sh[256];
  double s = 0.0;
  for (int k = threadIdx.x; k < KK; k += 256) {
    int c = counts[k];
    if (c > 0) {
      double p = (double)c / (double)(RQDEPTH * NN);
      s += p * log(p);
    }
  }
  sh[threadIdx.x] = s;
  __syncthreads();
  for (int st = 128; st; st >>= 1) {
    if (threadIdx.x < st) sh[threadIdx.x] += sh[threadIdx.x + st];
    __syncthreads();
  }
  if (threadIdx.x == 0) out[0] = (float)exp(-sh[0]);
}

extern "C" void kernel_launch(void* const* d_in, const int* in_sizes, int n_in,
                              void* d_out, int out_size, void* d_ws, size_t ws_size,
                              hipStream_t stream) {
  const float* z  = (const float*)d_in[0];
  const float* cb = (const float*)d_in[1];
  float* out = (float*)d_out;
  const size_t PLANE = (size_t)NN * CC;          // 8,388,608
  float* cum  = out;                             // [4][B][C][H][W]
  float* zst  = out + (size_t)RQDEPTH * PLANE;   // [B][C][H][W]
  float* idxo = zst + PLANE;                     // [4][N]
  float* perp = idxo + (size_t)RQDEPTH * NN;     // scalar

  float* resid = (float*)d_ws;                   // N*C
  float* cbT   = resid + PLANE;                  // C*K
  float* Arow  = cbT + (size_t)CC * KK;          // N (slot kept, now unused)
  float* Bcol  = Arow + NN;                      // K
  int* idxAll  = (int*)(Bcol + KK);              // D*N
  int* counts  = idxAll + RQDEPTH * NN;          // K

  dim3 tgrid(HWt / 32, CC / 32, BB);             // 32 x 8 x 32
  k_ztrans<<<tgrid, 256, 0, stream>>>(z, resid);
  dim3 cgrid(KK / 32, CC / 32);
  k_cbtrans<<<cgrid, 256, 0, stream>>>(cb, cbT);
  k_bnorm<<<KK / 256, 256, 0, stream>>>(cb, Bcol);
  k_zero<<<(KK + 255) / 256, 256, 0, stream>>>(counts);

  for (int d = 0; d < RQDEPTH; ++d) {
    k_bulk<<<NN / 16, 256, 0, stream>>>(resid, cbT, Bcol, idxAll,
                                        idxo + (size_t)d * NN, counts, d);
    k_update<<<tgrid, 256, 0, stream>>>(cb, idxAll, resid, cum, zst, d);
  }
  k_perp<<<1, 256, 0, stream>>>(counts, perp);
}

// Round 2
// 1884.896 us; speedup vs baseline: 1.7703x; 1.7703x over previous
//
#include <hip/hip_runtime.h>
#include <math.h>

#define BB 32
#define CC 256
#define HWt 1024          // H*W
#define NN 32768          // B*H*W
#define KK 2048
#define RQDEPTH 4

// ===== numpy pairwise sum-of-squares, blocksize-128 tree, bit-exact =====
__device__ __forceinline__ float pw128sq(const float4* __restrict__ a4) {
  float r[8];
  {
    float4 p = a4[0], q = a4[1];
    r[0] = __fmul_rn(p.x, p.x); r[1] = __fmul_rn(p.y, p.y);
    r[2] = __fmul_rn(p.z, p.z); r[3] = __fmul_rn(p.w, p.w);
    r[4] = __fmul_rn(q.x, q.x); r[5] = __fmul_rn(q.y, q.y);
    r[6] = __fmul_rn(q.z, q.z); r[7] = __fmul_rn(q.w, q.w);
  }
  for (int i = 1; i < 16; ++i) {
    float4 p = a4[2 * i], q = a4[2 * i + 1];
    r[0] = __fadd_rn(r[0], __fmul_rn(p.x, p.x));
    r[1] = __fadd_rn(r[1], __fmul_rn(p.y, p.y));
    r[2] = __fadd_rn(r[2], __fmul_rn(p.z, p.z));
    r[3] = __fadd_rn(r[3], __fmul_rn(p.w, p.w));
    r[4] = __fadd_rn(r[4], __fmul_rn(q.x, q.x));
    r[5] = __fadd_rn(r[5], __fmul_rn(q.y, q.y));
    r[6] = __fadd_rn(r[6], __fmul_rn(q.z, q.z));
    r[7] = __fadd_rn(r[7], __fmul_rn(q.w, q.w));
  }
  return __fadd_rn(__fadd_rn(__fadd_rn(r[0], r[1]), __fadd_rn(r[2], r[3])),
                   __fadd_rn(__fadd_rn(r[4], r[5]), __fadd_rn(r[6], r[7])));
}

// ---------------- prep: z [B,C,H,W] -> resid [N,C] ----------------
__global__ void k_ztrans(const float* __restrict__ z, float* __restrict__ resid) {
  __shared__ float tile[32][33];
  int b = blockIdx.z, c0 = blockIdx.y * 32, hw0 = blockIdx.x * 32;
  int tx = threadIdx.x & 31, ty = threadIdx.x >> 5;
  for (int i = ty; i < 32; i += 8)
    tile[i][tx] = z[((size_t)b * CC + c0 + i) * HWt + hw0 + tx];
  __syncthreads();
  for (int i = ty; i < 32; i += 8)
    resid[((size_t)b * HWt + hw0 + i) * CC + c0 + tx] = tile[tx][i];
}

// ---------------- prep: cb [K,C] -> cbT [C,K] ----------------
__global__ void k_cbtrans(const float* __restrict__ cb, float* __restrict__ cbT) {
  __shared__ float tile[32][33];
  int k0 = blockIdx.x * 32, c0 = blockIdx.y * 32;
  int tx = threadIdx.x & 31, ty = threadIdx.x >> 5;
  for (int i = ty; i < 32; i += 8)
    tile[i][tx] = cb[(size_t)(k0 + i) * CC + c0 + tx];
  __syncthreads();
  for (int i = ty; i < 32; i += 8)
    cbT[(size_t)(c0 + i) * KK + k0 + tx] = tile[tx][i];
}

// ---------------- B_k = np.sum(cb**2, axis=1) bit-exact ----------------
__global__ void k_bnorm(const float* __restrict__ cb, float* __restrict__ Bcol) {
  int k = blockIdx.x * 256 + threadIdx.x;
  if (k >= KK) return;
  const float4* row = (const float4*)(cb + (size_t)k * CC);
  Bcol[k] = __fadd_rn(pw128sq(row), pw128sq(row + 32));
}

// ---------------- A_n = np.sum(resid**2, axis=1) bit-exact ----------------
__global__ void k_anorm(const float* __restrict__ resid, float* __restrict__ Arow) {
  int n = blockIdx.x * 256 + threadIdx.x;
  if (n >= NN) return;
  const float4* row = (const float4*)(resid + (size_t)n * CC);
  Arow[n] = __fadd_rn(pw128sq(row), pw128sq(row + 32));
}

__global__ void k_zero(int* counts) {
  int t = blockIdx.x * 256 + threadIdx.x;
  if (t < KK) counts[t] = 0;
}

// ---------------- bulk: np fp32 dists + first-argmin, ILP-restructured ----------
// Identical math/argmin to the verified round-0 kernel (strict c-ascending fmaf
// per (n,k), fl(A+B) - 2*acc, u64 (dist,k) lex first-argmin). ONE change:
// E (cbT fragments) is double-buffered with prefetch distance 1 -- the 4
// global_load_dwordx4 for c4+1 are issued BEFORE the 256-FMA block of c4, so
// the ~200-300 cy L2 latency is covered by FMA issue instead of a vmcnt stall
// at each iteration top. z stays on the wave-uniform s_load path (SGPRs, zero
// VGPR cost). Register budget: acc 64 + E0/E1 32 + temps -- fits bounds(256,4).
#define LOADE(E, C4V)                                                          \
  {                                                                            \
    _Pragma("unroll")                                                          \
    for (int cs = 0; cs < 4; ++cs)                                             \
      *(float4*)((E) + 4 * cs) =                                               \
          ((const float4*)(cbT + (size_t)(4 * (C4V) + cs) * KK + kbase))[lane];\
  }

#define FMAB(E, C4V)                                                           \
  {                                                                            \
    _Pragma("unroll")                                                          \
    for (int r = 0; r < 16; ++r) {                                             \
      const float4 z4 = *(const float4*)(zb + (size_t)r * CC + 4 * (C4V));     \
      _Pragma("unroll")                                                        \
      for (int j = 0; j < 4; ++j) {                                            \
        float a = acc[r][j];                                                   \
        a = fmaf(z4.x, (E)[0 * 4 + j], a);  /* strict c-ascending chain */     \
        a = fmaf(z4.y, (E)[1 * 4 + j], a);                                     \
        a = fmaf(z4.z, (E)[2 * 4 + j], a);                                     \
        a = fmaf(z4.w, (E)[3 * 4 + j], a);                                     \
        acc[r][j] = a;                                                         \
      }                                                                        \
    }                                                                          \
  }

__global__ __launch_bounds__(256, 4) void k_bulk(const float* __restrict__ resid,
                                                 const float* __restrict__ cbT,
                                                 const float* __restrict__ Arow,
                                                 const float* __restrict__ Bcol,
                                                 int* __restrict__ idxAll,
                                                 float* __restrict__ idxOut,
                                                 int* __restrict__ counts, int depth) {
  __shared__ unsigned long long sm[4][2][16];
  const int wave = __builtin_amdgcn_readfirstlane((int)(threadIdx.x >> 6));
  const int lane = threadIdx.x & 63;
  const int row0 = blockIdx.x * 16;
  const float* zb = resid + (size_t)row0 * CC;   // wave-uniform base

  float av[16];
#pragma unroll
  for (int r = 0; r < 16; ++r) av[r] = Arow[row0 + r];   // uniform -> SGPR

  for (int pass = 0; pass < 2; ++pass) {
    const int kbase = wave * 512 + pass * 256;
    float acc[16][4];
#pragma unroll
    for (int r = 0; r < 16; ++r)
#pragma unroll
      for (int j = 0; j < 4; ++j) acc[r][j] = 0.f;

    float E0[16], E1[16];
    LOADE(E0, 0);

#pragma unroll 1
    for (int c4 = 0; c4 < 62; c4 += 2) {
      LOADE(E1, c4 + 1);   // prefetch next column-block
      FMAB(E0, c4);        // 256 FMAs cover the load latency
      LOADE(E0, c4 + 2);
      FMAB(E1, c4 + 1);
    }
    // tail: c4 = 62, 63
    LOADE(E1, 63);
    FMAB(E0, 62);
    FMAB(E1, 63);

    // epilogue: dists + exact lex first-argmin for this pass
    float bk[4];
    *(float4*)bk = ((const float4*)(Bcol + kbase))[lane];
#pragma unroll
    for (int r = 0; r < 16; ++r) {
      unsigned long long b = ~0ull;
#pragma unroll
      for (int j = 0; j < 4; ++j) {
        float Cv = __fadd_rn(av[r], bk[j]);                      // fl32(A + B)
        float s  = __fsub_rn(Cv, __fadd_rn(acc[r][j], acc[r][j]));  // fl32(C - 2M)
        unsigned long long pk =
            ((unsigned long long)__float_as_uint(s) << 32) |
            (unsigned int)(kbase + lane * 4 + j);
        if (pk < b) b = pk;
      }
      for (int m = 1; m < 64; m <<= 1) {
        unsigned long long o = __shfl_xor(b, m);
        if (o < b) b = o;
      }
      if (lane == 0) sm[wave][pass][r] = b;
    }
  }
  __syncthreads();
  // merge 4 waves x 2 passes per row
  if (threadIdx.x < 16) {
    unsigned long long b = ~0ull;
#pragma unroll
    for (int w = 0; w < 4; ++w)
#pragma unroll
      for (int p = 0; p < 2; ++p)
        if (sm[w][p][threadIdx.x] < b) b = sm[w][p][threadIdx.x];
    int wi = (int)(unsigned int)(b & 0xffffffffu);
    int n = row0 + (int)threadIdx.x;
    idxAll[depth * NN + n] = wi;
    idxOut[n] = (float)wi;
    atomicAdd(counts + wi, 1);
  }
}

// ------- update: resid -= q (fp32, np order), cum[d] = cum[d-1] + q, zst at d=3 -------
__global__ void k_update(const float* __restrict__ cb, const int* __restrict__ idxAll,
                         float* __restrict__ resid, float* __restrict__ cum,
                         float* __restrict__ zst, int depth) {
  __shared__ float qt[32][33];
  __shared__ float rt[32][33];
  int b = blockIdx.z, c0 = blockIdx.y * 32, hw0 = blockIdx.x * 32;
  int tx = threadIdx.x & 31, ty = threadIdx.x >> 5;
  const int* idx = idxAll + depth * NN;
  for (int i = ty; i < 32; i += 8) {
    int n = b * HWt + hw0 + i;
    int kk = idx[n];
    size_t fo = (size_t)n * CC + c0 + tx;
    float q = cb[(size_t)kk * CC + c0 + tx];
    float r = __fsub_rn(resid[fo], q);
    resid[fo] = r;
    qt[i][tx] = q;
    rt[i][tx] = r;
  }
  __syncthreads();
  const size_t PLANE = (size_t)NN * CC;
  for (int i = ty; i < 32; i += 8) {
    size_t oo = ((size_t)b * CC + c0 + i) * HWt + hw0 + tx;
    float q = qt[tx][i];
    float prevv = (depth == 0) ? 0.f : cum[(size_t)(depth - 1) * PLANE + oo];
    cum[(size_t)depth * PLANE + oo] = __fadd_rn(prevv, q);
    if (depth == 3) zst[oo] = rt[tx][i];
  }
}

// ---------------- perplexity ----------------
__global__ void k_perp(const int* __restrict__ counts, float* __restrict__ out) {
  __shared__ double sh[256];
  double s = 0.0;
  for (int k = threadIdx.x; k < KK; k += 256) {
    int c = counts[k];
    if (c > 0) {
      double p = (double)c / (double)(RQDEPTH * NN);
      s += p * log(p);
    }
  }
  sh[threadIdx.x] = s;
  __syncthreads();
  for (int st = 128; st; st >>= 1) {
    if (threadIdx.x < st) sh[threadIdx.x] += sh[threadIdx.x + st];
    __syncthreads();
  }
  if (threadIdx.x == 0) out[0] = (float)exp(-sh[0]);
}

extern "C" void kernel_launch(void* const* d_in, const int* in_sizes, int n_in,
                              void* d_out, int out_size, void* d_ws, size_t ws_size,
                              hipStream_t stream) {
  const float* z  = (const float*)d_in[0];
  const float* cb = (const float*)d_in[1];
  float* out = (float*)d_out;
  const size_t PLANE = (size_t)NN * CC;          // 8,388,608
  float* cum  = out;                             // [4][B][C][H][W]
  float* zst  = out + (size_t)RQDEPTH * PLANE;   // [B][C][H][W]
  float* idxo = zst + PLANE;                     // [4][N]
  float* perp = idxo + (size_t)RQDEPTH * NN;     // scalar

  float* resid = (float*)d_ws;                   // N*C
  float* cbT   = resid + PLANE;                  // C*K
  float* Arow  = cbT + (size_t)CC * KK;          // N
  float* Bcol  = Arow + NN;                      // K
  int* idxAll  = (int*)(Bcol + KK);              // D*N
  int* counts  = idxAll + RQDEPTH * NN;          // K

  dim3 tgrid(HWt / 32, CC / 32, BB);             // 32 x 8 x 32
  k_ztrans<<<tgrid, 256, 0, stream>>>(z, resid);
  dim3 cgrid(KK / 32, CC / 32);
  k_cbtrans<<<cgrid, 256, 0, stream>>>(cb, cbT);
  k_bnorm<<<KK / 256, 256, 0, stream>>>(cb, Bcol);
  k_zero<<<(KK + 255) / 256, 256, 0, stream>>>(counts);

  for (int d = 0; d < RQDEPTH; ++d) {
    k_anorm<<<NN / 256, 256, 0, stream>>>(resid, Arow);
    k_bulk<<<NN / 16, 256, 0, stream>>>(resid, cbT, Arow, Bcol, idxAll,
                                        idxo + (size_t)d * NN, counts, d);
    k_update<<<tgrid, 256, 0, stream>>>(cb, idxAll, resid, cum, zst, d);
  }
  k_perp<<<1, 256, 0, stream>>>(counts, perp);
}